// Round 2
// baseline (327.241 us; speedup 1.0000x reference)
//
#include <hip/hip_runtime.h>

#define NN 50000
#define EE 800000
#define RR 8
#define DD 128
#define SS (NN*RR)        // 400000 segments
#define TE (2*EE)         // 1600000 directed edges
#define NB 782            // dst buckets of 64 nodes
#define NBLK 391          // partition blocks, 4096 directed edges each
#define NS (NB*NBLK)      // 305762 scan elements

typedef __attribute__((ext_vector_type(8))) short bf16x8;
typedef __attribute__((ext_vector_type(4))) float f32x4;

__device__ __forceinline__ unsigned short f2bf(float f){
  unsigned int u = __float_as_uint(f);
  u += 0x7fffu + ((u >> 16) & 1u);   // round-to-nearest-even
  return (unsigned short)(u >> 16);
}
__device__ __forceinline__ float bf_lo(unsigned int w){ return __uint_as_float(w << 16); }
__device__ __forceinline__ float bf_hi(unsigned int w){ return __uint_as_float(w & 0xffff0000u); }

__device__ __forceinline__ void acc8(float* a, uint4 u){
  a[0] += bf_lo(u.x); a[1] += bf_hi(u.x);
  a[2] += bf_lo(u.y); a[3] += bf_hi(u.y);
  a[4] += bf_lo(u.z); a[5] += bf_hi(u.z);
  a[6] += bf_lo(u.w); a[7] += bf_hi(u.w);
}
__device__ __forceinline__ unsigned int pack2(float a, float b){
  return ((unsigned int)f2bf(b) << 16) | (unsigned int)f2bf(a);
}

// directed edge j in [0,TE): j<EE forward (s->d), else reversed
__device__ __forceinline__ void dir_edge(const int* ei, const int* et, int j,
                                         int& s, int& d, int& t){
  if (j < EE){ s = ei[j]; d = ei[EE + j]; t = et[j]; }
  else { int jj = j - EE; s = ei[EE + jj]; d = ei[jj]; t = et[jj]; }
}

// ---- partition phase A1: per-(bucket,block) histogram ---------------------
__global__ __launch_bounds__(256) void k_hist(const int* __restrict__ ei,
                                              const int* __restrict__ et,
                                              int* __restrict__ hist){
  __shared__ int h[NB];
  int tid = threadIdx.x, bid = blockIdx.x;
  for (int i = tid; i < NB; i += 256) h[i] = 0;
  __syncthreads();
  int j0 = bid*4096;
  for (int k = tid; k < 4096; k += 256){
    int j = j0 + k;
    if (j < TE){
      int s, d, t; dir_edge(ei, et, j, s, d, t);
      atomicAdd(&h[d >> 6], 1);           // LDS atomic
    }
  }
  __syncthreads();
  for (int i = tid; i < NB; i += 256) hist[i*NBLK + bid] = h[i];
}

// ---- scan over NS elements (in-place exclusive), 3 kernels ----------------
__global__ __launch_bounds__(256) void k_scan1(int* __restrict__ hist,
                                               int* __restrict__ blksum){
  __shared__ int sd[256];
  int b = blockIdx.x, tid = threadIdx.x;
  int base = b*1024 + tid*4;
  int v0 = (base+0 < NS) ? hist[base+0] : 0;
  int v1 = (base+1 < NS) ? hist[base+1] : 0;
  int v2 = (base+2 < NS) ? hist[base+2] : 0;
  int v3 = (base+3 < NS) ? hist[base+3] : 0;
  int ts = v0+v1+v2+v3;
  sd[tid] = ts; __syncthreads();
  for (int o = 1; o < 256; o <<= 1){
    int t = (tid >= o) ? sd[tid-o] : 0;
    __syncthreads();
    sd[tid] += t;
    __syncthreads();
  }
  int ex = sd[tid] - ts;
  if (base+0 < NS) hist[base+0] = ex; ex += v0;
  if (base+1 < NS) hist[base+1] = ex; ex += v1;
  if (base+2 < NS) hist[base+2] = ex; ex += v2;
  if (base+3 < NS) hist[base+3] = ex;
  if (tid == 255) blksum[b] = sd[255];
}

__global__ __launch_bounds__(512) void k_scan2(int* __restrict__ blksum, int nb){
  __shared__ int sd[512];
  int tid = threadIdx.x;
  int v = (tid < nb) ? blksum[tid] : 0;
  sd[tid] = v; __syncthreads();
  for (int o = 1; o < 512; o <<= 1){
    int t = (tid >= o) ? sd[tid-o] : 0;
    __syncthreads();
    sd[tid] += t;
    __syncthreads();
  }
  if (tid < nb) blksum[tid] = sd[tid] - v;   // exclusive
}

__global__ __launch_bounds__(256) void k_scan3(int* __restrict__ hist,
                                               const int* __restrict__ blksum){
  int i = blockIdx.x*blockDim.x + threadIdx.x;
  if (i < NS) hist[i] += blksum[i >> 10];
}

// ---- partition phase A3: place packed edges into bucket slices ------------
// packed: src (17b) | dstlo (6b @17) | rel (3b @23)
__global__ __launch_bounds__(256) void k_part(const int* __restrict__ ei,
                                              const int* __restrict__ et,
                                              const int* __restrict__ S,
                                              unsigned int* __restrict__ P){
  __shared__ int cur[NB];
  int tid = threadIdx.x, bid = blockIdx.x;
  for (int i = tid; i < NB; i += 256) cur[i] = S[i*NBLK + bid];
  __syncthreads();
  int j0 = bid*4096;
  for (int k = tid; k < 4096; k += 256){
    int j = j0 + k;
    if (j < TE){
      int s, d, t; dir_edge(ei, et, j, s, d, t);
      int b = d >> 6;
      int p = atomicAdd(&cur[b], 1);       // LDS atomic rank
      P[p] = (unsigned int)s | ((unsigned int)(d & 63) << 17)
           | ((unsigned int)t << 23);
    }
  }
}

// ---- phase B: per-bucket counting sort -> offs + esrc ---------------------
__global__ __launch_bounds__(256) void k_build(const unsigned int* __restrict__ P,
                                               const int* __restrict__ S,
                                               int* __restrict__ esrc,
                                               int* __restrict__ offs){
  __shared__ int h[512], cu[512], sd[256];
  int tid = threadIdx.x, b = blockIdx.x;
  int pstart = S[b*NBLK];
  int pend   = (b+1 < NB) ? S[(b+1)*NBLK] : TE;
  int ne = pend - pstart;
  h[2*tid] = 0; h[2*tid+1] = 0;
  __syncthreads();
  for (int k = tid; k < ne; k += 256){
    unsigned int u = P[pstart + k];
    int lseg = (int)(((u >> 17) & 63u)*8u + (u >> 23));
    atomicAdd(&h[lseg], 1);                // LDS atomic
  }
  __syncthreads();
  // exclusive scan of 512 bins with 256 threads
  int v0 = h[2*tid], v1 = h[2*tid+1];
  int ts = v0 + v1;
  sd[tid] = ts; __syncthreads();
  for (int o = 1; o < 256; o <<= 1){
    int t = (tid >= o) ? sd[tid-o] : 0;
    __syncthreads();
    sd[tid] += t;
    __syncthreads();
  }
  int ex = sd[tid] - ts;
  cu[2*tid]   = pstart + ex;
  cu[2*tid+1] = pstart + ex + v0;
  int seg0 = b*512;
  if (seg0 + 2*tid     < SS) offs[seg0 + 2*tid]     = cu[2*tid];
  if (seg0 + 2*tid + 1 < SS) offs[seg0 + 2*tid + 1] = cu[2*tid+1];
  if (b == NB-1 && tid == 0) offs[SS] = TE;
  __syncthreads();
  for (int k = tid; k < ne; k += 256){
    unsigned int u = P[pstart + k];
    int lseg = (int)(((u >> 17) & 63u)*8u + (u >> 23));
    int r = atomicAdd(&cu[lseg], 1);       // LDS atomic
    esrc[r] = (int)(u & 0x1ffffu);
  }
}

// ---- merged conversions: x->bf16, W/self_W -> bf16 transposed -------------
__global__ __launch_bounds__(256) void k_conv(const float* __restrict__ x,
                                              const float* __restrict__ w,
                                              const float* __restrict__ sw,
                                              unsigned short* __restrict__ xb,
                                              unsigned short* __restrict__ wb){
  int i = blockIdx.x*blockDim.x + threadIdx.x;
  const int M1 = NN*DD/4;            // 1,600,000 float4 groups
  if (i < M1){
    float4 v = ((const float4*)x)[i];
    ushort4 o;
    o.x = f2bf(v.x); o.y = f2bf(v.y); o.z = f2bf(v.z); o.w = f2bf(v.w);
    ((ushort4*)xb)[i] = o;
  } else {
    int j = i - M1;
    if (j < 9*DD*DD){
      int r = j >> 14; int rem = j & 16383; int n = rem >> 7; int k = rem & 127;
      float v = (r < 8) ? w[r*16384 + k*128 + n] : sw[k*128 + n];
      wb[j] = f2bf(v);
    }
  }
}

// ---- burst-of-4 masked row-load helper ------------------------------------
// lb = group's base LANE in the wave (idx values live in lanes lb..lb+15)
__device__ __forceinline__ void issue4(const unsigned short* __restrict__ xb,
                                       int idxw, int lb, int gl,
                                       int ebase, int n, uint4 (&u)[4]){
  #pragma unroll
  for (int e = 0; e < 4; ++e){
    u[e] = make_uint4(0u,0u,0u,0u);
    if (e < n){
      int s = __shfl(idxw, lb + ebase + e);
      u[e] = *(const uint4*)(xb + (size_t)s*DD + gl*8);
    }
  }
}

// ---- fused gather + degree-scale + GEMM (16-row tile, 4 blocks/CU) --------
// Block: 256 threads, 16 dst rows (NN % 16 == 0, no guards needed).
// LDS A = [16 rows][8*128 + 8 pad] bf16 = 33,024 B -> 4 blocks/CU.
// Self-loop slot is NOT staged: in phase 2 it is read from xb directly in
// MFMA fragment layout (row = l15, cols = ks*32 + quad*8).
// Phase 1: each 16-lane group gathers 8 segments (1 row x 8 rels):
//   - wave-coalesced offs load (32 consecutive entries, lanes 0..31)
//   - all 8 esrc index vectors preloaded (8 loads in flight)
//   - segment pairs processed with 1-deep prefetched first burst
// Phase 2 (after ONE barrier): 16x128 GEMM over K = 9*128.
__global__ __launch_bounds__(256, 4) void k_fused(
    const unsigned short* __restrict__ xb,
    const unsigned short* __restrict__ wb,
    const int* __restrict__ offs,
    const int* __restrict__ esrc,
    float* __restrict__ out)
{
  __shared__ __align__(16) unsigned short A[16][1032]; // 33,024 B
  const int tid  = threadIdx.x;
  const int wave = tid >> 6, lane = tid & 63;
  const int l15  = lane & 15, quad = lane >> 4;
  const int g    = quad;            // gather group within wave (0..3)
  const int gl   = l15;             // lane within group
  const int sb   = g << 3;          // group's CSR-segment base lane (8 segs)
  const int lb   = g << 4;          // group's base lane (idx values live here)
  const int rowbase = blockIdx.x * 16;
  const int rowl = 4*wave + g;      // the one row this group owns

  // ---- wave-wide CSR: lane l<32 holds segment (row 4w+(l>>3), rel l&7) ----
  int voff = 0, vcnt = 0;
  if (lane < 32){
    int oidx = (rowbase + 4*wave)*8 + lane;
    voff = offs[oidx];
    vcnt = offs[oidx + 1] - voff;    // offs[SS] = TE sentinel makes this safe
  }

  // ---- preload up to 16 source indices for each of the group's 8 segs ----
  int idxv[8];
  #pragma unroll
  for (int i = 0; i < 8; ++i){
    int off = __shfl(voff, sb + i);
    int cnt = __shfl(vcnt, sb + i);
    idxv[i] = (gl < cnt) ? esrc[off + gl] : 0;
  }

  // ---- prologue: first burst of pair 0 ------------------------------------
  uint4 U0[2][4], U1[2][4];
  {
    int c0 = __shfl(vcnt, sb + 0); c0 = c0 < 4 ? c0 : 4;
    int c1 = __shfl(vcnt, sb + 1); c1 = c1 < 4 ? c1 : 4;
    issue4(xb, idxv[0], lb, gl, 0, c0, U0[0]);
    issue4(xb, idxv[1], lb, gl, 0, c1, U1[0]);
  }

  // ---- segment pairs: process cur while next pair's first burst in flight -
  #pragma unroll
  for (int ii = 0; ii < 8; ii += 2){
    const int cur = (ii >> 1) & 1;   // compile-time after full unroll
    const int nxt = cur ^ 1;
    if (ii + 2 < 8){
      int c0 = __shfl(vcnt, sb + ii + 2); c0 = c0 < 4 ? c0 : 4;
      int c1 = __shfl(vcnt, sb + ii + 3); c1 = c1 < 4 ? c1 : 4;
      issue4(xb, idxv[ii+2], lb, gl, 0, c0, U0[nxt]);
      issue4(xb, idxv[ii+3], lb, gl, 0, c1, U1[nxt]);
    }
    int cnt0 = __shfl(vcnt, sb + ii),     cnt1 = __shfl(vcnt, sb + ii + 1);
    int off0 = __shfl(voff, sb + ii),     off1 = __shfl(voff, sb + ii + 1);
    int cm0  = cnt0 < 16 ? cnt0 : 16,     cm1  = cnt1 < 16 ? cnt1 : 16;
    float a0[8] = {0.f,0.f,0.f,0.f,0.f,0.f,0.f,0.f};
    float a1[8] = {0.f,0.f,0.f,0.f,0.f,0.f,0.f,0.f};
    #pragma unroll
    for (int e = 0; e < 4; ++e){ acc8(a0, U0[cur][e]); acc8(a1, U1[cur][e]); }
    int e0 = cm0 < 4 ? cm0 : 4, e1 = cm1 < 4 ? cm1 : 4;
    while (e0 < cm0 || e1 < cm1){
      int n0 = cm0 - e0; n0 = n0 < 0 ? 0 : (n0 > 4 ? 4 : n0);
      int n1 = cm1 - e1; n1 = n1 < 0 ? 0 : (n1 > 4 ? 4 : n1);
      uint4 t0[4], t1[4];
      issue4(xb, idxv[ii],   lb, gl, e0, n0, t0);
      issue4(xb, idxv[ii+1], lb, gl, e1, n1, t1);
      #pragma unroll
      for (int e = 0; e < 4; ++e){ acc8(a0, t0[e]); acc8(a1, t1[e]); }
      e0 += n0; e1 += n1;
    }
    if (cnt0 > 16){
      for (int e2 = 16; e2 < cnt0; ++e2){
        int s = esrc[off0 + e2];
        uint4 u = *(const uint4*)(xb + (size_t)s*DD + gl*8);
        acc8(a0, u);
      }
    }
    if (cnt1 > 16){
      for (int e2 = 16; e2 < cnt1; ++e2){
        int s = esrc[off1 + e2];
        uint4 u = *(const uint4*)(xb + (size_t)s*DD + gl*8);
        acc8(a1, u);
      }
    }
    float s0 = cnt0 > 0 ? 1.0f/(float)cnt0 : 0.f;
    float s1 = cnt1 > 0 ? 1.0f/(float)cnt1 : 0.f;
    uint4 w0, w1;
    w0.x = pack2(a0[0]*s0, a0[1]*s0);
    w0.y = pack2(a0[2]*s0, a0[3]*s0);
    w0.z = pack2(a0[4]*s0, a0[5]*s0);
    w0.w = pack2(a0[6]*s0, a0[7]*s0);
    w1.x = pack2(a1[0]*s1, a1[1]*s1);
    w1.y = pack2(a1[2]*s1, a1[3]*s1);
    w1.z = pack2(a1[4]*s1, a1[5]*s1);
    w1.w = pack2(a1[6]*s1, a1[7]*s1);
    *(uint4*)&A[rowl][(ii    )*128 + gl*8] = w0;
    *(uint4*)&A[rowl][(ii + 1)*128 + gl*8] = w1;
  }

  __syncthreads();   // the ONLY barrier

  // ---- phase 2: 16x128 GEMM over K = 9*128 --------------------------------
  f32x4 C[2];
  C[0] = (f32x4)(0.f); C[1] = (f32x4)(0.f);

  #pragma unroll
  for (int rr = 0; rr < 9; ++rr){
    const unsigned short* wr = wb + rr * 16384;
    bf16x8 bfrag[2][4];
    #pragma unroll
    for (int nt = 0; nt < 2; ++nt)
      #pragma unroll
      for (int ks = 0; ks < 4; ++ks)
        bfrag[nt][ks] = *(const bf16x8*)(wr + (wave*32 + nt*16 + l15)*128 + ks*32 + quad*8);
    #pragma unroll
    for (int ks = 0; ks < 4; ++ks){
      bf16x8 af;
      if (rr < 8) af = *(const bf16x8*)&A[l15][rr*128 + ks*32 + quad*8];
      else        af = *(const bf16x8*)(xb + (size_t)(rowbase + l15)*DD + ks*32 + quad*8);
      C[0] = __builtin_amdgcn_mfma_f32_16x16x32_bf16(af, bfrag[0][ks], C[0], 0, 0, 0);
      C[1] = __builtin_amdgcn_mfma_f32_16x16x32_bf16(af, bfrag[1][ks], C[1], 0, 0, 0);
    }
  }

  #pragma unroll
  for (int nt = 0; nt < 2; ++nt){
    #pragma unroll
    for (int i = 0; i < 4; ++i){
      int row = quad*4 + i;
      int col = wave*32 + nt*16 + l15;
      out[(size_t)(rowbase + row)*DD + col] = C[nt][i];
    }
  }
}

// ---- workspace layout (bytes) ---------------------------------------------
// xb     @ 0          : NN*DD*2 = 12,800,000
//   (aliased during partition: hist @ 0 (1,223,168), blksum @ 1,223,168
//    (2,048), P @ 1,225,216 (6,400,000) — all dead before k_conv writes xb)
// esrc   @ 12,800,000 : TE*4    = 6,400,000
// offs   @ 19,200,000 : (SS+1)*4 -> 1,600,016
// wb     @ 20,800,016 : 9*DD*DD*2 = 294,912
// total 21,094,928
extern "C" void kernel_launch(void* const* d_in, const int* in_sizes, int n_in,
                              void* d_out, int out_size, void* d_ws, size_t ws_size,
                              hipStream_t stream){
  const float* x  = (const float*)d_in[0];
  const float* w  = (const float*)d_in[1];
  const float* sw = (const float*)d_in[2];
  const int*   ei = (const int*)d_in[3];
  const int*   et = (const int*)d_in[4];
  float* out = (float*)d_out;
  char* ws = (char*)d_ws;

  if (ws_size < (size_t)21100000) return;

  unsigned short* xb = (unsigned short*)(ws + 0);
  int*          hist = (int*)(ws + 0);               // alias (dead before xb)
  int*        blksum = (int*)(ws + 1223168);         // alias
  unsigned int*    P = (unsigned int*)(ws + 1225216);// alias
  int*          esrc = (int*)(ws + 12800000);
  int*          offs = (int*)(ws + 19200000);
  unsigned short* wb = (unsigned short*)(ws + 20800016);

  k_hist <<<NBLK, 256, 0, stream>>>(ei, et, hist);
  k_scan1<<<(NS + 1023)/1024, 256, 0, stream>>>(hist, blksum);   // 299 blocks
  k_scan2<<<1, 512, 0, stream>>>(blksum, (NS + 1023)/1024);
  k_scan3<<<(NS + 255)/256, 256, 0, stream>>>(hist, blksum);
  k_part <<<NBLK, 256, 0, stream>>>(ei, et, hist, P);
  k_build<<<NB, 256, 0, stream>>>(P, hist, esrc, offs);
  k_conv <<<(NN*DD/4 + 9*DD*DD + 255)/256, 256, 0, stream>>>(x, w, sw, xb, wb);
  k_fused<<<NN/16, 256, 0, stream>>>(xb, wb, offs, esrc, out);
}

// Round 3
// 257.568 us; speedup vs baseline: 1.2705x; 1.2705x over previous
//
#include <hip/hip_runtime.h>

#define NN 50000
#define EE 800000
#define RR 8
#define DD 128
#define SS (NN*RR)        // 400000 segments
#define TE (2*EE)         // 1600000 directed edges
#define NB 782            // dst buckets of 64 nodes
#define NBLK 391          // partition blocks, 4096 directed edges each
#define NS (NB*NBLK)      // 305762 scan elements

typedef __attribute__((ext_vector_type(8))) short bf16x8;
typedef __attribute__((ext_vector_type(4))) float f32x4;

__device__ __forceinline__ unsigned short f2bf(float f){
  unsigned int u = __float_as_uint(f);
  u += 0x7fffu + ((u >> 16) & 1u);   // round-to-nearest-even
  return (unsigned short)(u >> 16);
}
__device__ __forceinline__ float bf_lo(unsigned int w){ return __uint_as_float(w << 16); }
__device__ __forceinline__ float bf_hi(unsigned int w){ return __uint_as_float(w & 0xffff0000u); }

__device__ __forceinline__ void acc8(float* a, uint4 u){
  a[0] += bf_lo(u.x); a[1] += bf_hi(u.x);
  a[2] += bf_lo(u.y); a[3] += bf_hi(u.y);
  a[4] += bf_lo(u.z); a[5] += bf_hi(u.z);
  a[6] += bf_lo(u.w); a[7] += bf_hi(u.w);
}
__device__ __forceinline__ unsigned int pack2(float a, float b){
  return ((unsigned int)f2bf(b) << 16) | (unsigned int)f2bf(a);
}

// directed edge j in [0,TE): j<EE forward (s->d), else reversed
__device__ __forceinline__ void dir_edge(const int* ei, const int* et, int j,
                                         int& s, int& d, int& t){
  if (j < EE){ s = ei[j]; d = ei[EE + j]; t = et[j]; }
  else { int jj = j - EE; s = ei[EE + jj]; d = ei[jj]; t = et[jj]; }
}

// ---- partition phase A1: per-(bucket,block) histogram ---------------------
__global__ __launch_bounds__(256) void k_hist(const int* __restrict__ ei,
                                              const int* __restrict__ et,
                                              int* __restrict__ hist){
  __shared__ int h[NB];
  int tid = threadIdx.x, bid = blockIdx.x;
  for (int i = tid; i < NB; i += 256) h[i] = 0;
  __syncthreads();
  int j0 = bid*4096;
  for (int k = tid; k < 4096; k += 256){
    int j = j0 + k;
    if (j < TE){
      int s, d, t; dir_edge(ei, et, j, s, d, t);
      atomicAdd(&h[d >> 6], 1);           // LDS atomic
    }
  }
  __syncthreads();
  for (int i = tid; i < NB; i += 256) hist[i*NBLK + bid] = h[i];
}

// ---- scan over NS elements (in-place exclusive), 3 kernels ----------------
__global__ __launch_bounds__(256) void k_scan1(int* __restrict__ hist,
                                               int* __restrict__ blksum){
  __shared__ int sd[256];
  int b = blockIdx.x, tid = threadIdx.x;
  int base = b*1024 + tid*4;
  int v0 = (base+0 < NS) ? hist[base+0] : 0;
  int v1 = (base+1 < NS) ? hist[base+1] : 0;
  int v2 = (base+2 < NS) ? hist[base+2] : 0;
  int v3 = (base+3 < NS) ? hist[base+3] : 0;
  int ts = v0+v1+v2+v3;
  sd[tid] = ts; __syncthreads();
  for (int o = 1; o < 256; o <<= 1){
    int t = (tid >= o) ? sd[tid-o] : 0;
    __syncthreads();
    sd[tid] += t;
    __syncthreads();
  }
  int ex = sd[tid] - ts;
  if (base+0 < NS) hist[base+0] = ex; ex += v0;
  if (base+1 < NS) hist[base+1] = ex; ex += v1;
  if (base+2 < NS) hist[base+2] = ex; ex += v2;
  if (base+3 < NS) hist[base+3] = ex;
  if (tid == 255) blksum[b] = sd[255];
}

__global__ __launch_bounds__(512) void k_scan2(int* __restrict__ blksum, int nb){
  __shared__ int sd[512];
  int tid = threadIdx.x;
  int v = (tid < nb) ? blksum[tid] : 0;
  sd[tid] = v; __syncthreads();
  for (int o = 1; o < 512; o <<= 1){
    int t = (tid >= o) ? sd[tid-o] : 0;
    __syncthreads();
    sd[tid] += t;
    __syncthreads();
  }
  if (tid < nb) blksum[tid] = sd[tid] - v;   // exclusive
}

__global__ __launch_bounds__(256) void k_scan3(int* __restrict__ hist,
                                               const int* __restrict__ blksum){
  int i = blockIdx.x*blockDim.x + threadIdx.x;
  if (i < NS) hist[i] += blksum[i >> 10];
}

// ---- partition phase A3: place packed edges into bucket slices ------------
// packed: src (17b) | dstlo (6b @17) | rel (3b @23)
__global__ __launch_bounds__(256) void k_part(const int* __restrict__ ei,
                                              const int* __restrict__ et,
                                              const int* __restrict__ S,
                                              unsigned int* __restrict__ P){
  __shared__ int cur[NB];
  int tid = threadIdx.x, bid = blockIdx.x;
  for (int i = tid; i < NB; i += 256) cur[i] = S[i*NBLK + bid];
  __syncthreads();
  int j0 = bid*4096;
  for (int k = tid; k < 4096; k += 256){
    int j = j0 + k;
    if (j < TE){
      int s, d, t; dir_edge(ei, et, j, s, d, t);
      int b = d >> 6;
      int p = atomicAdd(&cur[b], 1);       // LDS atomic rank
      P[p] = (unsigned int)s | ((unsigned int)(d & 63) << 17)
           | ((unsigned int)t << 23);
    }
  }
}

// ---- phase B: per-bucket counting sort -> offs + esrc ---------------------
__global__ __launch_bounds__(256) void k_build(const unsigned int* __restrict__ P,
                                               const int* __restrict__ S,
                                               int* __restrict__ esrc,
                                               int* __restrict__ offs){
  __shared__ int h[512], cu[512], sd[256];
  int tid = threadIdx.x, b = blockIdx.x;
  int pstart = S[b*NBLK];
  int pend   = (b+1 < NB) ? S[(b+1)*NBLK] : TE;
  int ne = pend - pstart;
  h[2*tid] = 0; h[2*tid+1] = 0;
  __syncthreads();
  for (int k = tid; k < ne; k += 256){
    unsigned int u = P[pstart + k];
    int lseg = (int)(((u >> 17) & 63u)*8u + (u >> 23));
    atomicAdd(&h[lseg], 1);                // LDS atomic
  }
  __syncthreads();
  // exclusive scan of 512 bins with 256 threads
  int v0 = h[2*tid], v1 = h[2*tid+1];
  int ts = v0 + v1;
  sd[tid] = ts; __syncthreads();
  for (int o = 1; o < 256; o <<= 1){
    int t = (tid >= o) ? sd[tid-o] : 0;
    __syncthreads();
    sd[tid] += t;
    __syncthreads();
  }
  int ex = sd[tid] - ts;
  cu[2*tid]   = pstart + ex;
  cu[2*tid+1] = pstart + ex + v0;
  int seg0 = b*512;
  if (seg0 + 2*tid     < SS) offs[seg0 + 2*tid]     = cu[2*tid];
  if (seg0 + 2*tid + 1 < SS) offs[seg0 + 2*tid + 1] = cu[2*tid+1];
  if (b == NB-1 && tid == 0) offs[SS] = TE;
  __syncthreads();
  for (int k = tid; k < ne; k += 256){
    unsigned int u = P[pstart + k];
    int lseg = (int)(((u >> 17) & 63u)*8u + (u >> 23));
    int r = atomicAdd(&cu[lseg], 1);       // LDS atomic
    esrc[r] = (int)(u & 0x1ffffu);
  }
}

// ---- merged conversions: x->bf16, W/self_W -> bf16 transposed -------------
__global__ __launch_bounds__(256) void k_conv(const float* __restrict__ x,
                                              const float* __restrict__ w,
                                              const float* __restrict__ sw,
                                              unsigned short* __restrict__ xb,
                                              unsigned short* __restrict__ wb){
  int i = blockIdx.x*blockDim.x + threadIdx.x;
  const int M1 = NN*DD/4;            // 1,600,000 float4 groups
  if (i < M1){
    float4 v = ((const float4*)x)[i];
    ushort4 o;
    o.x = f2bf(v.x); o.y = f2bf(v.y); o.z = f2bf(v.z); o.w = f2bf(v.w);
    ((ushort4*)xb)[i] = o;
  } else {
    int j = i - M1;
    if (j < 9*DD*DD){
      int r = j >> 14; int rem = j & 16383; int n = rem >> 7; int k = rem & 127;
      float v = (r < 8) ? w[r*16384 + k*128 + n] : sw[k*128 + n];
      wb[j] = f2bf(v);
    }
  }
}

// ---- fused gather + degree-scale + GEMM (R0 skeleton + 3-level pipeline) --
// 32-row tile, 9 rounds, double-buffered LDS (best measured structure).
// Pipeline: offs hoisted to registers (one coalesced load); esrc index
// vectors loaded one round ahead; 8-deep row bursts issued BEFORE the GEMM
// (bfrag loads issued first so the MFMA vmcnt wait leaves row loads in
// flight); finish (wait+acc+pack+LDS write) after the GEMM.
__global__ __launch_bounds__(256, 3) void k_fused(
    const unsigned short* __restrict__ xb,
    const unsigned short* __restrict__ wb,
    const int* __restrict__ offs,
    const int* __restrict__ esrc,
    float* __restrict__ out)
{
  __shared__ __align__(16) unsigned short Alds[2][32][136]; // +8 pad, 17,408 B
  const int tid  = threadIdx.x;
  const int wave = tid >> 6, lane = tid & 63;
  const int l15  = lane & 15, quad = lane >> 4;
  const int g    = quad;            // gather group within wave (0..3)
  const int gl   = l15;            // lane within group
  const int lb   = g << 4;         // group's base lane
  const int rowbase = blockIdx.x * 32;

  // ---- self rows: zero-dependency, issue at t=0 ---------------------------
  uint4 selfU[2];
  #pragma unroll
  for (int p = 0; p < 2; ++p){
    int gd = rowbase + wave*8 + 2*g + p;
    selfU[p] = make_uint4(0u,0u,0u,0u);
    if (gd < NN) selfU[p] = *(const uint4*)(xb + (size_t)gd*DD + gl*8);
  }

  // ---- hoisted CSR: lane l holds seg (row wave*8 + (l>>3), rel l&7) -------
  int sidx = (rowbase + wave*8)*8 + lane;
  int voff = 0, vcnt = 0;
  if (sidx < SS){
    voff = offs[sidx];
    vcnt = offs[sidx + 1] - voff;   // offs[SS] = TE sentinel makes this safe
  }

  // ---- pipeline state -----------------------------------------------------
  int idxbuf[2][2];                  // [parity][row-pair p]
  uint4 U[2][8];                     // current in-flight row bursts

  auto issue_idx = [&](int rq, int bi){
    #pragma unroll
    for (int p = 0; p < 2; ++p){
      int sl  = (2*g + p)*8 + rq;
      int off = __shfl(voff, sl);
      int cnt = __shfl(vcnt, sl);
      idxbuf[bi][p] = 0;
      if (gl < cnt) idxbuf[bi][p] = esrc[off + gl];
    }
  };

  auto issue_bursts = [&](int rq, int bi){
    #pragma unroll
    for (int p = 0; p < 2; ++p){
      int sl  = (2*g + p)*8 + rq;
      int cnt = __shfl(vcnt, sl);
      int cm  = cnt < 8 ? cnt : 8;
      #pragma unroll
      for (int e = 0; e < 8; ++e){
        U[p][e] = make_uint4(0u,0u,0u,0u);
        if (e < cm){
          int s = __shfl(idxbuf[bi][p], lb + e);
          U[p][e] = *(const uint4*)(xb + (size_t)s*DD + gl*8);
        }
      }
    }
  };

  auto finish = [&](int rq, int bi, int lbuf){
    #pragma unroll
    for (int p = 0; p < 2; ++p){
      int sl  = (2*g + p)*8 + rq;
      int cnt = __shfl(vcnt, sl);
      int off = __shfl(voff, sl);
      float a[8] = {0.f,0.f,0.f,0.f,0.f,0.f,0.f,0.f};
      #pragma unroll
      for (int e = 0; e < 8; ++e) acc8(a, U[p][e]);
      int cm16 = cnt < 16 ? cnt : 16;
      for (int e2 = 8; e2 < cm16; ++e2){        // rare: P(cnt>8) ~ 2%
        int s = __shfl(idxbuf[bi][p], lb + e2);
        uint4 u = *(const uint4*)(xb + (size_t)s*DD + gl*8);
        acc8(a, u);
      }
      for (int e2 = 16; e2 < cnt; ++e2){
        int s = esrc[off + e2];
        uint4 u = *(const uint4*)(xb + (size_t)s*DD + gl*8);
        acc8(a, u);
      }
      float sc = (cnt > 0) ? (1.0f / (float)cnt) : 0.f;
      uint4 w0;
      w0.x = pack2(a[0]*sc, a[1]*sc);
      w0.y = pack2(a[2]*sc, a[3]*sc);
      w0.z = pack2(a[4]*sc, a[5]*sc);
      w0.w = pack2(a[6]*sc, a[7]*sc);
      int rowl = wave*8 + 2*g + p;
      *(uint4*)&Alds[lbuf][rowl][gl*8] = w0;
    }
  };

  // ---- prologue: rel 0 gathered un-overlapped (one-time) ------------------
  issue_idx(0, 0);
  issue_idx(1, 1);
  issue_bursts(0, 0);
  finish(0, 0, 0);
  __syncthreads();

  f32x4 C[2][2];
  #pragma unroll
  for (int m = 0; m < 2; ++m){ C[m][0] = (f32x4)(0.f); C[m][1] = (f32x4)(0.f); }

  // ---- 9 rounds, fully unrolled (static U/idx/LDS-buffer indexing) --------
  #pragma unroll
  for (int rr = 0; rr < 9; ++rr){
    // (1) bfrag loads FIRST (oldest vmem -> MFMA wait leaves row loads live)
    const unsigned short* wr = wb + rr * 16384;
    bf16x8 bfrag[2][4];
    #pragma unroll
    for (int nt = 0; nt < 2; ++nt)
      #pragma unroll
      for (int ks = 0; ks < 4; ++ks)
        bfrag[nt][ks] = *(const bf16x8*)(wr + (wave*32 + nt*16 + l15)*128 + ks*32 + quad*8);

    // (2) issue next relation's row bursts (consumes idx loaded last round)
    if (rr < 7) issue_bursts(rr + 1, (rr + 1) & 1);
    // (3) issue idx two relations ahead
    if (rr <= 5) issue_idx(rr + 2, rr & 1);

    // (4) GEMM(rr) from LDS buffer written last round
    #pragma unroll
    for (int m = 0; m < 2; ++m){
      #pragma unroll
      for (int ks = 0; ks < 4; ++ks){
        bf16x8 af = *(const bf16x8*)&Alds[rr & 1][m*16 + l15][ks*32 + quad*8];
        C[m][0] = __builtin_amdgcn_mfma_f32_16x16x32_bf16(af, bfrag[0][ks], C[m][0], 0, 0, 0);
        C[m][1] = __builtin_amdgcn_mfma_f32_16x16x32_bf16(af, bfrag[1][ks], C[m][1], 0, 0, 0);
      }
    }

    // (5) finish next relation: wait rows, acc, tails, pack, LDS write
    if (rr < 7) finish(rr + 1, (rr + 1) & 1, (rr + 1) & 1);
    if (rr == 7){
      #pragma unroll
      for (int p = 0; p < 2; ++p){
        int rowl = wave*8 + 2*g + p;
        *(uint4*)&Alds[0][rowl][gl*8] = selfU[p];   // slot for round 8
      }
    }
    if (rr < 8) __syncthreads();
  }

  #pragma unroll
  for (int m = 0; m < 2; ++m){
    #pragma unroll
    for (int nt = 0; nt < 2; ++nt){
      #pragma unroll
      for (int i = 0; i < 4; ++i){
        int row = m*16 + quad*4 + i;
        int gd  = rowbase + row;
        int col = wave*32 + nt*16 + l15;
        if (gd < NN) out[gd*DD + col] = C[m][nt][i];
      }
    }
  }
}

// ---- workspace layout (bytes) ---------------------------------------------
// xb     @ 0          : NN*DD*2 = 12,800,000
//   (aliased during partition: hist @ 0 (1,223,168), blksum @ 1,223,168
//    (2,048), P @ 1,225,216 (6,400,000) — all dead before k_conv writes xb)
// esrc   @ 12,800,000 : TE*4    = 6,400,000
// offs   @ 19,200,000 : (SS+1)*4 -> 1,600,016
// wb     @ 20,800,016 : 9*DD*DD*2 = 294,912
// total 21,094,928
extern "C" void kernel_launch(void* const* d_in, const int* in_sizes, int n_in,
                              void* d_out, int out_size, void* d_ws, size_t ws_size,
                              hipStream_t stream){
  const float* x  = (const float*)d_in[0];
  const float* w  = (const float*)d_in[1];
  const float* sw = (const float*)d_in[2];
  const int*   ei = (const int*)d_in[3];
  const int*   et = (const int*)d_in[4];
  float* out = (float*)d_out;
  char* ws = (char*)d_ws;

  if (ws_size < (size_t)21100000) return;

  unsigned short* xb = (unsigned short*)(ws + 0);
  int*          hist = (int*)(ws + 0);               // alias (dead before xb)
  int*        blksum = (int*)(ws + 1223168);         // alias
  unsigned int*    P = (unsigned int*)(ws + 1225216);// alias
  int*          esrc = (int*)(ws + 12800000);
  int*          offs = (int*)(ws + 19200000);
  unsigned short* wb = (unsigned short*)(ws + 20800016);

  k_hist <<<NBLK, 256, 0, stream>>>(ei, et, hist);
  k_scan1<<<(NS + 1023)/1024, 256, 0, stream>>>(hist, blksum);   // 299 blocks
  k_scan2<<<1, 512, 0, stream>>>(blksum, (NS + 1023)/1024);
  k_scan3<<<(NS + 255)/256, 256, 0, stream>>>(hist, blksum);
  k_part <<<NBLK, 256, 0, stream>>>(ei, et, hist, P);
  k_build<<<NB, 256, 0, stream>>>(P, hist, esrc, offs);
  k_conv <<<(NN*DD/4 + 9*DD*DD + 255)/256, 256, 0, stream>>>(x, w, sw, xb, wb);
  k_fused<<<(NN + 31)/32, 256, 0, stream>>>(xb, wb, offs, esrc, out);
}